// Round 5
// baseline (1056.243 us; speedup 1.0000x reference)
//
#include <hip/hip_runtime.h>
#include <math.h>

#define N 1024
#define F 4096
#define NLAYERS 24
#define VOCAB 50277
#define GRID 256
#define BLOCK 512   // 8 waves/block, 1 block per CU

// barrier region (in ws at byte offset 32768):
//   arrive[256] flags, one 64B line each; release[32] copies
#define BAR_OFF_BYTES 32768
#define ARRIVE_STRIDE 16
#define RELEASE_OFF (256 * ARRIVE_STRIDE)
#define BAR_DWORDS (256 * ARRIVE_STRIDE + 32 * ARRIVE_STRIDE)

__device__ __forceinline__ float dot4(float4 a, float4 b) {
  return fmaf(a.x, b.x, fmaf(a.y, b.y, fmaf(a.z, b.z, a.w * b.w)));
}
__device__ __forceinline__ float wred(float v) {
#pragma unroll
  for (int o = 32; o > 0; o >>= 1) v += __shfl_down(v, o, 64);
  return v;
}
__device__ __forceinline__ float bfly(float v) {
#pragma unroll
  for (int o = 1; o < 64; o <<= 1) v += __shfl_xor(v, o, 64);
  return v;
}
__device__ __forceinline__ float sigmoidf(float x) { return 1.f / (1.f + expf(-x)); }

// coherent (agent-scope) ops: performed at the device coherent point
__device__ __forceinline__ float ld_c(const float* p) {
  return __hip_atomic_load(p, __ATOMIC_RELAXED, __HIP_MEMORY_SCOPE_AGENT);
}
__device__ __forceinline__ void st_c(float* p, float v) {
  __hip_atomic_store(p, v, __ATOMIC_RELAXED, __HIP_MEMORY_SCOPE_AGENT);
}
__device__ __forceinline__ unsigned ld_cu(const unsigned* p) {
  return __hip_atomic_load(p, __ATOMIC_RELAXED, __HIP_MEMORY_SCOPE_AGENT);
}
__device__ __forceinline__ void st_cu(unsigned* p, unsigned v) {
  __hip_atomic_store(p, v, __ATOMIC_RELAXED, __HIP_MEMORY_SCOPE_AGENT);
}

// intra-block barrier: LDS visibility only (no vmcnt drain)
__device__ __forceinline__ void lbar() {
  asm volatile("s_waitcnt lgkmcnt(0)" ::: "memory");
  __builtin_amdgcn_s_barrier();
}

// grid barrier: per-block arrival flags on separate lines, parallel sweep by
// block 0 wave 0, release broadcast to 32 spread copies. Explicit full drain
// (vmcnt for st_c data, lgkm for LDS) happens exactly once, here.
__device__ __forceinline__ void gbar(unsigned* bar, unsigned gen, int blk, int tid) {
  asm volatile("s_waitcnt vmcnt(0) lgkmcnt(0)" ::: "memory");
  __builtin_amdgcn_s_barrier();
  if (tid == 0) st_cu(bar + blk * ARRIVE_STRIDE, gen);
  if (blk == 0) {
    if (tid < 64) {
      for (;;) {
        bool ok = true;
#pragma unroll
        for (int i = 0; i < 4; ++i)
          ok &= (ld_cu(bar + (tid * 4 + i) * ARRIVE_STRIDE) >= gen);
        if (__all(ok)) break;
        __builtin_amdgcn_s_sleep(2);
      }
      if (tid < 32) st_cu(bar + RELEASE_OFF + tid * ARRIVE_STRIDE, gen);
    }
  } else if (tid == 0) {
    while (ld_cu(bar + RELEASE_OFF + (blk & 31) * ARRIVE_STRIDE) < gen)
      __builtin_amdgcn_s_sleep(2);
  }
  __builtin_amdgcn_s_barrier();
}

// redundant-per-wave LayerNorm of the 16 lane-columns held in q[4]
__device__ __forceinline__ void ln16(float4* q, const float* __restrict__ w,
                                     const float* __restrict__ b, int lane) {
  float s = 0.f, sq = 0.f;
#pragma unroll
  for (int k = 0; k < 4; ++k) {
    s += q[k].x + q[k].y + q[k].z + q[k].w;
    sq += dot4(q[k], q[k]);
  }
  s = bfly(s);
  sq = bfly(sq);
  float mu = s * (1.f / N);
  float rstd = rsqrtf(sq * (1.f / N) - mu * mu + 1e-5f);
#pragma unroll
  for (int k = 0; k < 4; ++k) {
    float4 w4 = ((const float4*)w)[(k << 6) + lane];
    float4 b4 = ((const float4*)b)[(k << 6) + lane];
    q[k].x = (q[k].x - mu) * rstd * w4.x + b4.x;
    q[k].y = (q[k].y - mu) * rstd * w4.y + b4.y;
    q[k].z = (q[k].z - mu) * rstd * w4.z + b4.z;
    q[k].w = (q[k].w - mu) * rstd * w4.w + b4.w;
  }
}

__device__ __forceinline__ float4 mix4(float4 a, float4 s, float4 m) {
  float4 r;
  r.x = a.x * m.x + s.x * (1.f - m.x);
  r.y = a.y * m.y + s.y * (1.f - m.y);
  r.z = a.z * m.z + s.z * (1.f - m.z);
  r.w = a.w * m.w + s.w * (1.f - m.w);
  return r;
}

__device__ __forceinline__ void wkv1(float k, float v, float r, float aa, float bb,
                                     float pp, float tf, float td, float& rab,
                                     float& naa, float& nbb, float& npp) {
  float ww = tf + k;
  float q = fmaxf(pp, ww);
  float e1 = expf(pp - q);
  float e2 = expf(ww - q);
  float a = e1 * aa + e2 * v;
  float b = e1 * bb + e2;
  rab = r * a / b;
  float ww2 = pp + td;
  float q2 = fmaxf(ww2, k);
  float f1 = expf(ww2 - q2);
  float f2 = expf(k - q2);
  naa = f1 * aa + f2 * v;
  nbb = f1 * bb + f2;
  npp = q2;
}

__global__ __launch_bounds__(BLOCK, 1) void k_rwkv(
    const int* __restrict__ ctx, const float* __restrict__ state,
    const float* __restrict__ emb, const float* __restrict__ ln0w,
    const float* __restrict__ ln0b, const float* __restrict__ ln1w,
    const float* __restrict__ ln1b, const float* __restrict__ amk,
    const float* __restrict__ amv, const float* __restrict__ amr,
    const float* __restrict__ tf, const float* __restrict__ td,
    const float* __restrict__ kw, const float* __restrict__ vw,
    const float* __restrict__ rw, const float* __restrict__ ow,
    const float* __restrict__ ln2w, const float* __restrict__ ln2b,
    const float* __restrict__ fmk, const float* __restrict__ fmr,
    const float* __restrict__ fkw, const float* __restrict__ fvw,
    const float* __restrict__ frw, const float* __restrict__ lnoutw,
    const float* __restrict__ lnoutb, const float* __restrict__ head,
    float* __restrict__ out, float* __restrict__ ws, unsigned* __restrict__ bar) {
  __shared__ __align__(16) float s_vx[N];       // layer input x (read in stage B)
  __shared__ __align__(16) float s_tmp[3 * N];  // staging: k/v/r, sx, xf
  __shared__ __align__(16) float s_kk[16];

  const int tid = threadIdx.x;
  const int lane = tid & 63;
  const int wid = tid >> 6;
  const int blk = blockIdx.x;

  float* logits = out;
  float* st_out = out + VOCAB;
  float* sxbuf = ws;
  float* kbuf = ws + N;
  float* vbuf = ws + 2 * N;
  float* rbuf = ws + 3 * N;
  float* r2buf = ws + 4 * N;
  float* facc = ws + 5 * N;
  unsigned genc = 0;

  for (int l = 0; l < NLAYERS; ++l) {
    const size_t nn = (size_t)N * N;
    const float* st_l = state + (size_t)l * 5 * N;
    float* sto = st_out + (size_t)l * 5 * N;
    const float* kw_l = kw + l * nn;
    const float* vw_l = vw + l * nn;
    const float* rw_l = rw + l * nn;
    const float* ow_l = ow + l * nn;
    const float* fkw_l = fkw + (size_t)l * F * N;
    const float* fvw_l = fvw + (size_t)l * N * F;
    const float* frw_l = frw + l * nn;

    // ================= Stage A: x, LN1, mix, k/v/r GEMVs =================
    {
      // --- prefetch weight rows (independent of barrier data) ---
      int m0 = wid >> 2;                        // 0: kw row, 1: vw row
      int r0 = (blk << 2) + (wid & 3);
      const float* W0 = (m0 == 0 ? kw_l : vw_l) + (size_t)r0 * N;
      float4 a0[4], a1[4];
#pragma unroll
      for (int k = 0; k < 4; ++k) a0[k] = ((const float4*)W0)[(k << 6) + lane];
      int r1 = (blk << 2) + wid;                // rw row (wid<4)
      if (wid < 4) {
        const float* W1 = rw_l + (size_t)r1 * N;
#pragma unroll
        for (int k = 0; k < 4; ++k) a1[k] = ((const float4*)W1)[(k << 6) + lane];
      }
      // --- stage x into LDS ---
      int i0 = 2 * tid;
      float2 xin;
      if (l == 0) {
        int t1 = ctx[1], t0c = ctx[0];
        float e1a = emb[(size_t)t1 * N + i0], e1b = emb[(size_t)t1 * N + i0 + 1];
        float e0a = emb[(size_t)t0c * N + i0], e0b = emb[(size_t)t0c * N + i0 + 1];
        xin.x = (e1a * 4.f + e0a) * 0.2f;
        xin.y = (e1b * 4.f + e0b) * 0.2f;
      } else {
        xin.x = ld_c(sxbuf + i0) + ld_c(r2buf + i0) * ld_c(facc + i0);
        xin.y = ld_c(sxbuf + i0 + 1) + ld_c(r2buf + i0 + 1) * ld_c(facc + i0 + 1);
      }
      ((float2*)s_vx)[tid] = xin;
      lbar();
      float4 xq[4];
#pragma unroll
      for (int k = 0; k < 4; ++k) xq[k] = ((const float4*)s_vx)[(k << 6) + lane];
      if (l == 0) {
        ln16(xq, ln0w, ln0b, lane);
        lbar();  // all waves done reading raw values
        if (wid == 0) {
#pragma unroll
          for (int k = 0; k < 4; ++k) ((float4*)s_vx)[(k << 6) + lane] = xq[k];
        }
        // visibility for stage B via gbar's lgkm drain
      }
      // LN1 + mix (all in registers, redundant per wave)
      float4 xl[4];
#pragma unroll
      for (int k = 0; k < 4; ++k) xl[k] = xq[k];
      ln16(xl, ln1w + l * N, ln1b + l * N, lane);
      if (blk == 0 && wid == 0) {
#pragma unroll
        for (int k = 0; k < 4; ++k) ((float4*)(sto + N))[(k << 6) + lane] = xl[k];
      }
      float4 mkq[4], mvq[4], mrq[4];
#pragma unroll
      for (int k = 0; k < 4; ++k) {
        float4 s1 = ((const float4*)(st_l + N))[(k << 6) + lane];
        mkq[k] = mix4(xl[k], s1, ((const float4*)(amk + l * N))[(k << 6) + lane]);
        mvq[k] = mix4(xl[k], s1, ((const float4*)(amv + l * N))[(k << 6) + lane]);
        mrq[k] = mix4(xl[k], s1, ((const float4*)(amr + l * N))[(k << 6) + lane]);
      }
      // dots
      float d0 = 0.f;
      if (m0 == 0) {
#pragma unroll
        for (int k = 0; k < 4; ++k) d0 += dot4(a0[k], mkq[k]);
      } else {
#pragma unroll
        for (int k = 0; k < 4; ++k) d0 += dot4(a0[k], mvq[k]);
      }
      d0 = wred(d0);
      if (lane == 0) {
        if (m0 == 0) st_c(kbuf + r0, d0);
        else st_c(vbuf + r0, d0);
      }
      if (wid < 4) {
        float d1 = 0.f;
#pragma unroll
        for (int k = 0; k < 4; ++k) d1 += dot4(a1[k], mrq[k]);
        d1 = wred(d1);
        if (lane == 0) st_c(rbuf + r1, sigmoidf(d1));
      }
    }
    gbar(bar, ++genc, blk, tid);

    // ================= Stage B: WKV (wave-redundant) + ow GEMV =================
    {
      float4 b0[4];
      int rB = (blk << 2) + wid;
      if (wid < 4) {
        const float* WB = ow_l + (size_t)rB * N;
#pragma unroll
        for (int k = 0; k < 4; ++k) b0[k] = ((const float4*)WB)[(k << 6) + lane];
      }
      if (tid < 4) st_c(facc + (blk << 2) + tid, 0.f);  // zero for Stage C adds
      int i0 = 2 * tid;
      float2 kk2, vv2, rr2;
      kk2.x = ld_c(kbuf + i0); kk2.y = ld_c(kbuf + i0 + 1);
      vv2.x = ld_c(vbuf + i0); vv2.y = ld_c(vbuf + i0 + 1);
      rr2.x = ld_c(rbuf + i0); rr2.y = ld_c(rbuf + i0 + 1);
      ((float2*)s_tmp)[tid] = kk2;
      ((float2*)(s_tmp + N))[tid] = vv2;
      ((float2*)(s_tmp + 2 * N))[tid] = rr2;
      lbar();
      float4 rab[4], naa[4], nbb[4], npp[4];
#pragma unroll
      for (int k = 0; k < 4; ++k) {
        float4 kq = ((const float4*)s_tmp)[(k << 6) + lane];
        float4 vq = ((const float4*)(s_tmp + N))[(k << 6) + lane];
        float4 rq = ((const float4*)(s_tmp + 2 * N))[(k << 6) + lane];
        float4 aa4 = ((const float4*)(st_l + 2 * N))[(k << 6) + lane];
        float4 bb4 = ((const float4*)(st_l + 3 * N))[(k << 6) + lane];
        float4 pp4 = ((const float4*)(st_l + 4 * N))[(k << 6) + lane];
        float4 tf4 = ((const float4*)(tf + l * N))[(k << 6) + lane];
        float4 td4 = ((const float4*)(td + l * N))[(k << 6) + lane];
        wkv1(kq.x, vq.x, rq.x, aa4.x, bb4.x, pp4.x, tf4.x, td4.x, rab[k].x, naa[k].x, nbb[k].x, npp[k].x);
        wkv1(kq.y, vq.y, rq.y, aa4.y, bb4.y, pp4.y, tf4.y, td4.y, rab[k].y, naa[k].y, nbb[k].y, npp[k].y);
        wkv1(kq.z, vq.z, rq.z, aa4.z, bb4.z, pp4.z, tf4.z, td4.z, rab[k].z, naa[k].z, nbb[k].z, npp[k].z);
        wkv1(kq.w, vq.w, rq.w, aa4.w, bb4.w, pp4.w, tf4.w, td4.w, rab[k].w, naa[k].w, nbb[k].w, npp[k].w);
      }
      if (blk == 0 && wid == 0) {
#pragma unroll
        for (int k = 0; k < 4; ++k) {
          ((float4*)(sto + 2 * N))[(k << 6) + lane] = naa[k];
          ((float4*)(sto + 3 * N))[(k << 6) + lane] = nbb[k];
          ((float4*)(sto + 4 * N))[(k << 6) + lane] = npp[k];
        }
      }
      if (wid < 4) {
        float d = 0.f;
#pragma unroll
        for (int k = 0; k < 4; ++k) d += dot4(b0[k], rab[k]);
        d = wred(d);
        if (lane == 0) st_c(sxbuf + rB, s_vx[rB] + d);
      }
    }
    gbar(bar, ++genc, blk, tid);

    // ====== Stage C: LN2, mix, ffn_k -> relu^2 -> fvw col-panel; ffn_r ======
    {
      float4 ck0[4], ck1[4], cr[4], fv0[4], fv1[4];
      int gk0 = (blk << 4) + wid, gk1 = gk0 + 8;
#pragma unroll
      for (int k = 0; k < 4; ++k)
        ck0[k] = ((const float4*)(fkw_l + (size_t)gk0 * N))[(k << 6) + lane];
#pragma unroll
      for (int k = 0; k < 4; ++k)
        ck1[k] = ((const float4*)(fkw_l + (size_t)gk1 * N))[(k << 6) + lane];
      int rR = (blk << 2) + wid - 4;
      if (wid >= 4) {
#pragma unroll
        for (int k = 0; k < 4; ++k)
          cr[k] = ((const float4*)(frw_l + (size_t)rR * N))[(k << 6) + lane];
      }
      int rv0 = (tid + (blk << 2)) & (N - 1);
      int rv1 = (tid + (blk << 2) + 512) & (N - 1);
      const float* fvb = fvw_l + (blk << 4);
#pragma unroll
      for (int i = 0; i < 4; ++i) fv0[i] = ((const float4*)(fvb + (size_t)rv0 * F))[i];
#pragma unroll
      for (int i = 0; i < 4; ++i) fv1[i] = ((const float4*)(fvb + (size_t)rv1 * F))[i];
      int i0 = 2 * tid;
      float2 sx2;
      sx2.x = ld_c(sxbuf + i0);
      sx2.y = ld_c(sxbuf + i0 + 1);
      ((float2*)s_tmp)[tid] = sx2;
      lbar();
      float4 x2q[4];
#pragma unroll
      for (int k = 0; k < 4; ++k) x2q[k] = ((const float4*)s_tmp)[(k << 6) + lane];
      ln16(x2q, ln2w + l * N, ln2b + l * N, lane);
      if (blk == 0 && wid == 0) {
#pragma unroll
        for (int k = 0; k < 4; ++k) ((float4*)sto)[(k << 6) + lane] = x2q[k];
      }
      float4 mkq[4], mrq[4];
#pragma unroll
      for (int k = 0; k < 4; ++k) {
        float4 s0 = ((const float4*)st_l)[(k << 6) + lane];
        mkq[k] = mix4(x2q[k], s0, ((const float4*)(fmk + l * N))[(k << 6) + lane]);
        mrq[k] = mix4(x2q[k], s0, ((const float4*)(fmr + l * N))[(k << 6) + lane]);
      }
      float d0 = 0.f, d1 = 0.f;
#pragma unroll
      for (int k = 0; k < 4; ++k) {
        d0 += dot4(ck0[k], mkq[k]);
        d1 += dot4(ck1[k], mkq[k]);
      }
      d0 = wred(d0);
      d1 = wred(d1);
      if (lane == 0) {
        float t0 = fmaxf(d0, 0.f);
        s_kk[wid] = t0 * t0;
        float t1 = fmaxf(d1, 0.f);
        s_kk[8 + wid] = t1 * t1;
      }
      if (wid >= 4) {
        float dr = 0.f;
#pragma unroll
        for (int k = 0; k < 4; ++k) dr += dot4(cr[k], mrq[k]);
        dr = wred(dr);
        if (lane == 0) st_c(r2buf + rR, sigmoidf(dr));
      }
      lbar();
      float4 K0 = ((const float4*)s_kk)[0];
      float4 K1 = ((const float4*)s_kk)[1];
      float4 K2 = ((const float4*)s_kk)[2];
      float4 K3 = ((const float4*)s_kk)[3];
      float dv0 = dot4(fv0[0], K0) + dot4(fv0[1], K1) + dot4(fv0[2], K2) + dot4(fv0[3], K3);
      float dv1 = dot4(fv1[0], K0) + dot4(fv1[1], K1) + dot4(fv1[2], K2) + dot4(fv1[3], K3);
      unsafeAtomicAdd(facc + rv0, dv0);
      unsafeAtomicAdd(facc + rv1, dv1);
    }
    gbar(bar, ++genc, blk, tid);
  }

  // ================= head: logits = head @ LN(x_final) =================
  {
    int i0 = 2 * tid;
    float2 xf2;
    xf2.x = ld_c(sxbuf + i0) + ld_c(r2buf + i0) * ld_c(facc + i0);
    xf2.y = ld_c(sxbuf + i0 + 1) + ld_c(r2buf + i0 + 1) * ld_c(facc + i0 + 1);
    ((float2*)s_tmp)[tid] = xf2;
    lbar();
    float4 xf[4];
#pragma unroll
    for (int k = 0; k < 4; ++k) xf[k] = ((const float4*)s_tmp)[(k << 6) + lane];
    ln16(xf, lnoutw, lnoutb, lane);
    int gw = (blk << 3) + wid;
    for (int base = gw * 4; base < VOCAB; base += GRID * 8 * 4) {
      float4 h[4][4];
#pragma unroll
      for (int rr = 0; rr < 4; ++rr) {
        int row = base + rr;
        if (row < VOCAB) {
          const float4* hp = (const float4*)(head + (size_t)row * N);
#pragma unroll
          for (int k = 0; k < 4; ++k) h[rr][k] = hp[(k << 6) + lane];
        }
      }
#pragma unroll
      for (int rr = 0; rr < 4; ++rr) {
        int row = base + rr;
        if (row < VOCAB) {
          float d = 0.f;
#pragma unroll
          for (int k = 0; k < 4; ++k) d += dot4(h[rr][k], xf[k]);
          d = wred(d);
          if (lane == 0) logits[row] = d;
        }
      }
    }
  }
}

extern "C" void kernel_launch(void* const* d_in, const int* in_sizes, int n_in,
                              void* d_out, int out_size, void* d_ws, size_t ws_size,
                              hipStream_t stream) {
  const int* ctx = (const int*)d_in[0];
  const float* state = (const float*)d_in[1];
  const float* emb = (const float*)d_in[2];
  const float* ln0w = (const float*)d_in[3];
  const float* ln0b = (const float*)d_in[4];
  const float* ln1w = (const float*)d_in[5];
  const float* ln1b = (const float*)d_in[6];
  const float* amk = (const float*)d_in[7];
  const float* amv = (const float*)d_in[8];
  const float* amr = (const float*)d_in[9];
  const float* tf = (const float*)d_in[10];
  const float* td = (const float*)d_in[11];
  const float* kw = (const float*)d_in[12];
  const float* vw = (const float*)d_in[13];
  const float* rw = (const float*)d_in[14];
  const float* ow = (const float*)d_in[15];
  const float* ln2w = (const float*)d_in[16];
  const float* ln2b = (const float*)d_in[17];
  const float* fmk = (const float*)d_in[18];
  const float* fmr = (const float*)d_in[19];
  const float* fkw = (const float*)d_in[20];
  const float* fvw = (const float*)d_in[21];
  const float* frw = (const float*)d_in[22];
  const float* lnoutw = (const float*)d_in[23];
  const float* lnoutb = (const float*)d_in[24];
  const float* head = (const float*)d_in[25];
  float* out = (float*)d_out;
  float* ws = (float*)d_ws;
  unsigned* bar = (unsigned*)((char*)d_ws + BAR_OFF_BYTES);

  hipMemsetAsync(bar, 0, BAR_DWORDS * sizeof(unsigned), stream);

  void* args[] = {&ctx, &state, &emb, &ln0w, &ln0b, &ln1w, &ln1b,
                  &amk, &amv, &amr, &tf, &td, &kw, &vw, &rw, &ow,
                  &ln2w, &ln2b, &fmk, &fmr, &fkw, &fvw, &frw,
                  &lnoutw, &lnoutb, &head, &out, &ws, &bar};
  hipLaunchCooperativeKernel((const void*)k_rwkv, dim3(GRID), dim3(BLOCK),
                             args, 0, stream);
}

// Round 6
// 893.485 us; speedup vs baseline: 1.1822x; 1.1822x over previous
//
#include <hip/hip_runtime.h>
#include <math.h>

#define N 1024
#define F 4096
#define NLAYERS 24
#define VOCAB 50277
#define GRID 256
#define BLOCK 512   // 8 waves/block, 1 block per CU

// barrier region (in ws at byte offset 32768):
//   arrive[256] flags, one 64B line each; release[32] copies
#define BAR_OFF_BYTES 32768
#define ARRIVE_STRIDE 16
#define RELEASE_OFF (256 * ARRIVE_STRIDE)
#define BAR_DWORDS (256 * ARRIVE_STRIDE + 32 * ARRIVE_STRIDE)

__device__ __forceinline__ float dot4(float4 a, float4 b) {
  return fmaf(a.x, b.x, fmaf(a.y, b.y, fmaf(a.z, b.z, a.w * b.w)));
}
__device__ __forceinline__ float wred(float v) {
#pragma unroll
  for (int o = 32; o > 0; o >>= 1) v += __shfl_down(v, o, 64);
  return v;
}
__device__ __forceinline__ float bfly(float v) {
#pragma unroll
  for (int o = 1; o < 64; o <<= 1) v += __shfl_xor(v, o, 64);
  return v;
}
__device__ __forceinline__ float sigmoidf(float x) { return 1.f / (1.f + expf(-x)); }

// coherent (agent-scope) ops at the device coherent point
__device__ __forceinline__ float2 ld_c2(const float* p) {
  unsigned long long u = __hip_atomic_load((const unsigned long long*)p,
                                           __ATOMIC_RELAXED, __HIP_MEMORY_SCOPE_AGENT);
  float2 f;
  f.x = __uint_as_float((unsigned)u);
  f.y = __uint_as_float((unsigned)(u >> 32));
  return f;
}
__device__ __forceinline__ void st_c(float* p, float v) {
  __hip_atomic_store(p, v, __ATOMIC_RELAXED, __HIP_MEMORY_SCOPE_AGENT);
}
__device__ __forceinline__ unsigned ld_cu(const unsigned* p) {
  return __hip_atomic_load(p, __ATOMIC_RELAXED, __HIP_MEMORY_SCOPE_AGENT);
}
__device__ __forceinline__ void st_cu(unsigned* p, unsigned v) {
  __hip_atomic_store(p, v, __ATOMIC_RELAXED, __HIP_MEMORY_SCOPE_AGENT);
}

// intra-block barrier: LDS visibility only
__device__ __forceinline__ void lbar() {
  asm volatile("s_waitcnt lgkmcnt(0)" ::: "memory");
  __builtin_amdgcn_s_barrier();
}

// ---- split grid barrier: arrive (drain + flag), then wait (poll) ----
// Prefetch loads issued BETWEEN arrive and wait overlap the poll window:
// vmcnt is per-wave, and only the polling lane's wave serializes on its own
// poll loads.
__device__ __forceinline__ void gbar_arrive(unsigned* bar, unsigned gen, int blk,
                                            int tid) {
  asm volatile("s_waitcnt vmcnt(0) lgkmcnt(0)" ::: "memory");
  __builtin_amdgcn_s_barrier();
  if (tid == 0) st_cu(bar + blk * ARRIVE_STRIDE, gen);
}
__device__ __forceinline__ void gbar_wait(unsigned* bar, unsigned gen, int blk,
                                          int wid, int lane) {
  if (blk == 0 && wid == 0) {
    for (;;) {
      bool ok = true;
#pragma unroll
      for (int i = 0; i < 4; ++i)
        ok &= (ld_cu(bar + (lane * 4 + i) * ARRIVE_STRIDE) >= gen);
      if (__all(ok)) break;
      __builtin_amdgcn_s_sleep(1);
    }
    if (lane < 32) st_cu(bar + RELEASE_OFF + lane * ARRIVE_STRIDE, gen);
  } else {
    if (lane == 0) {
      const unsigned* rel = bar + RELEASE_OFF + (((blk << 3) + wid) & 31) * ARRIVE_STRIDE;
      while (ld_cu(rel) < gen) __builtin_amdgcn_s_sleep(1);
    }
  }
}

// redundant-per-wave LayerNorm of the 16 lane-columns held in q[4]
__device__ __forceinline__ void ln16(float4* q, const float* __restrict__ w,
                                     const float* __restrict__ b, int lane) {
  float s = 0.f, sq = 0.f;
#pragma unroll
  for (int k = 0; k < 4; ++k) {
    s += q[k].x + q[k].y + q[k].z + q[k].w;
    sq += dot4(q[k], q[k]);
  }
  s = bfly(s);
  sq = bfly(sq);
  float mu = s * (1.f / N);
  float rstd = rsqrtf(sq * (1.f / N) - mu * mu + 1e-5f);
#pragma unroll
  for (int k = 0; k < 4; ++k) {
    float4 w4 = ((const float4*)w)[(k << 6) + lane];
    float4 b4 = ((const float4*)b)[(k << 6) + lane];
    q[k].x = (q[k].x - mu) * rstd * w4.x + b4.x;
    q[k].y = (q[k].y - mu) * rstd * w4.y + b4.y;
    q[k].z = (q[k].z - mu) * rstd * w4.z + b4.z;
    q[k].w = (q[k].w - mu) * rstd * w4.w + b4.w;
  }
}

__device__ __forceinline__ float4 mix4(float4 a, float4 s, float4 m) {
  float4 r;
  r.x = a.x * m.x + s.x * (1.f - m.x);
  r.y = a.y * m.y + s.y * (1.f - m.y);
  r.z = a.z * m.z + s.z * (1.f - m.z);
  r.w = a.w * m.w + s.w * (1.f - m.w);
  return r;
}

__device__ __forceinline__ void wkv1(float k, float v, float r, float aa, float bb,
                                     float pp, float tf, float td, float& rab,
                                     float& naa, float& nbb, float& npp) {
  float ww = tf + k;
  float q = fmaxf(pp, ww);
  float e1 = expf(pp - q);
  float e2 = expf(ww - q);
  float a = e1 * aa + e2 * v;
  float b = e1 * bb + e2;
  rab = r * a / b;
  float ww2 = pp + td;
  float q2 = fmaxf(ww2, k);
  float f1 = expf(ww2 - q2);
  float f2 = expf(k - q2);
  naa = f1 * aa + f2 * v;
  nbb = f1 * bb + f2;
  npp = q2;
}

__global__ __launch_bounds__(BLOCK, 1) void k_rwkv(
    const int* __restrict__ ctx, const float* __restrict__ state,
    const float* __restrict__ emb, const float* __restrict__ ln0w,
    const float* __restrict__ ln0b, const float* __restrict__ ln1w,
    const float* __restrict__ ln1b, const float* __restrict__ amk,
    const float* __restrict__ amv, const float* __restrict__ amr,
    const float* __restrict__ tf, const float* __restrict__ td,
    const float* __restrict__ kw, const float* __restrict__ vw,
    const float* __restrict__ rw, const float* __restrict__ ow,
    const float* __restrict__ ln2w, const float* __restrict__ ln2b,
    const float* __restrict__ fmk, const float* __restrict__ fmr,
    const float* __restrict__ fkw, const float* __restrict__ fvw,
    const float* __restrict__ frw, const float* __restrict__ lnoutw,
    const float* __restrict__ lnoutb, const float* __restrict__ head,
    float* __restrict__ out, float* __restrict__ ws, unsigned* __restrict__ bar) {
  __shared__ __align__(16) float s_vx[N];   // layer input x (read in stage B)
  __shared__ __align__(16) float s_tmp[N];  // staging: rab / sx / xf
  __shared__ __align__(16) float s_kk[16];

  const int tid = threadIdx.x;
  const int lane = tid & 63;
  const int wid = tid >> 6;
  const int blk = blockIdx.x;
  const int i0 = 2 * tid;
  const size_t nn = (size_t)N * N;

  float* logits = out;
  float* st_out = out + VOCAB;
  float* sxbuf = ws;
  float* kbuf = ws + N;
  float* vbuf = ws + 2 * N;
  float* rbuf = ws + 3 * N;
  float* r2buf = ws + 4 * N;
  float* facc = ws + 5 * N;
  unsigned genc = 0;

  // prefetch registers
  float4 pa0[4], pa1[4], pb[4], pk0[4], pk1[4], pcr[4], pf0[4], pf1[4];

  const int rA = (blk << 2) + (wid & 3);   // kw/vw/rw row for this wave
  const int rB = (blk << 2) + wid;         // ow row (wid<4)
  const int rR = (blk << 2) + (wid - 4);   // frw row (wid>=4)
  const int gk0 = (blk << 4) + wid;        // fkw rows
  const int gk1 = gk0 + 8;
  const int rv0 = (tid + (blk << 2)) & (N - 1);          // fvw panel rows
  const int rv1 = (tid + (blk << 2) + 512) & (N - 1);

  // ---- initial prefetch: stage A, layer 0 ----
  {
    const float* W0 = ((wid < 4) ? kw : vw) + (size_t)rA * N;
#pragma unroll
    for (int k = 0; k < 4; ++k) pa0[k] = ((const float4*)W0)[(k << 6) + lane];
    if (wid < 4) {
      const float* W1 = rw + (size_t)rA * N;
#pragma unroll
      for (int k = 0; k < 4; ++k) pa1[k] = ((const float4*)W1)[(k << 6) + lane];
    }
  }

  for (int l = 0; l < NLAYERS; ++l) {
    const float* st_l = state + (size_t)l * 5 * N;
    float* sto = st_out + (size_t)l * 5 * N;

    // ================= Stage A: x, LN1, mix, k/v/r GEMVs =================
    {
      float2 xin;
      if (l == 0) {
        int t1 = ctx[1], t0c = ctx[0];
        float2 e1 = ((const float2*)(emb + (size_t)t1 * N))[tid];
        float2 e0 = ((const float2*)(emb + (size_t)t0c * N))[tid];
        xin.x = (e1.x * 4.f + e0.x) * 0.2f;
        xin.y = (e1.y * 4.f + e0.y) * 0.2f;
      } else {
        float2 sx2 = ld_c2(sxbuf + i0);
        float2 r22 = ld_c2(r2buf + i0);
        float2 fa2 = ld_c2(facc + i0);
        xin.x = sx2.x + r22.x * fa2.x;
        xin.y = sx2.y + r22.y * fa2.y;
      }
      ((float2*)s_vx)[tid] = xin;
      lbar();
      float4 xq[4];
#pragma unroll
      for (int k = 0; k < 4; ++k) xq[k] = ((const float4*)s_vx)[(k << 6) + lane];
      if (l == 0) {
        ln16(xq, ln0w, ln0b, lane);   // xq = x (post-ln0)
        if (wid == 0) {
#pragma unroll
          for (int k = 0; k < 4; ++k) ((float4*)s_vx)[(k << 6) + lane] = xq[k];
        }
        // visible to stage B via gbar_arrive's lgkm drain + barrier
      }
      float4 xl[4];
#pragma unroll
      for (int k = 0; k < 4; ++k) xl[k] = xq[k];
      ln16(xl, ln1w + l * N, ln1b + l * N, lane);
      if (blk == 0 && wid == 0) {
#pragma unroll
        for (int k = 0; k < 4; ++k) ((float4*)(sto + N))[(k << 6) + lane] = xl[k];
      }
      if (wid < 4) {
        float4 mk[4], mr[4];
#pragma unroll
        for (int k = 0; k < 4; ++k) {
          float4 s1 = ((const float4*)(st_l + N))[(k << 6) + lane];
          mk[k] = mix4(xl[k], s1, ((const float4*)(amk + l * N))[(k << 6) + lane]);
          mr[k] = mix4(xl[k], s1, ((const float4*)(amr + l * N))[(k << 6) + lane]);
        }
        float d0 = 0.f, d1 = 0.f;
#pragma unroll
        for (int k = 0; k < 4; ++k) {
          d0 += dot4(pa0[k], mk[k]);
          d1 += dot4(pa1[k], mr[k]);
        }
        d0 = wred(d0);
        d1 = wred(d1);
        if (lane == 0) {
          st_c(kbuf + rA, d0);
          st_c(rbuf + rA, sigmoidf(d1));
        }
      } else {
        float4 mv[4];
#pragma unroll
        for (int k = 0; k < 4; ++k) {
          float4 s1 = ((const float4*)(st_l + N))[(k << 6) + lane];
          mv[k] = mix4(xl[k], s1, ((const float4*)(amv + l * N))[(k << 6) + lane]);
        }
        float d0 = 0.f;
#pragma unroll
        for (int k = 0; k < 4; ++k) d0 += dot4(pa0[k], mv[k]);
        d0 = wred(d0);
        if (lane == 0) st_c(vbuf + rA, d0);
      }
    }
    gbar_arrive(bar, ++genc, blk, tid);
    // ---- prefetch B weights during barrier wait ----
    if (wid < 4) {
      const float* WB = ow + l * nn + (size_t)rB * N;
#pragma unroll
      for (int k = 0; k < 4; ++k) pb[k] = ((const float4*)WB)[(k << 6) + lane];
    }
    gbar_wait(bar, genc, blk, wid, lane);

    // ================= Stage B: WKV (per-thread) + ow GEMV =================
    {
      if (tid < 4) st_c(facc + (blk << 2) + tid, 0.f);  // zero for stage C adds
      float2 k2 = ld_c2(kbuf + i0);
      float2 v2 = ld_c2(vbuf + i0);
      float2 r2v = ld_c2(rbuf + i0);
      float2 aa2 = ((const float2*)(st_l + 2 * N))[tid];
      float2 bb2 = ((const float2*)(st_l + 3 * N))[tid];
      float2 pp2 = ((const float2*)(st_l + 4 * N))[tid];
      float2 tf2 = ((const float2*)(tf + l * N))[tid];
      float2 td2 = ((const float2*)(td + l * N))[tid];
      float2 rab2, naa2, nbb2, npp2;
      wkv1(k2.x, v2.x, r2v.x, aa2.x, bb2.x, pp2.x, tf2.x, td2.x, rab2.x, naa2.x, nbb2.x, npp2.x);
      wkv1(k2.y, v2.y, r2v.y, aa2.y, bb2.y, pp2.y, tf2.y, td2.y, rab2.y, naa2.y, nbb2.y, npp2.y);
      ((float2*)s_tmp)[tid] = rab2;
      if (blk == 0) {
        ((float2*)(sto + 2 * N))[tid] = naa2;
        ((float2*)(sto + 3 * N))[tid] = nbb2;
        ((float2*)(sto + 4 * N))[tid] = npp2;
      }
      lbar();
      if (wid < 4) {
        float4 rq[4];
#pragma unroll
        for (int k = 0; k < 4; ++k) rq[k] = ((const float4*)s_tmp)[(k << 6) + lane];
        float d = 0.f;
#pragma unroll
        for (int k = 0; k < 4; ++k) d += dot4(pb[k], rq[k]);
        d = wred(d);
        if (lane == 0) st_c(sxbuf + rB, s_vx[rB] + d);
      }
    }
    gbar_arrive(bar, ++genc, blk, tid);
    // ---- prefetch C weights during barrier wait ----
    {
      const float* fkw_l = fkw + (size_t)l * F * N;
#pragma unroll
      for (int k = 0; k < 4; ++k)
        pk0[k] = ((const float4*)(fkw_l + (size_t)gk0 * N))[(k << 6) + lane];
#pragma unroll
      for (int k = 0; k < 4; ++k)
        pk1[k] = ((const float4*)(fkw_l + (size_t)gk1 * N))[(k << 6) + lane];
      if (wid >= 4) {
        const float* WR = frw + l * nn + (size_t)rR * N;
#pragma unroll
        for (int k = 0; k < 4; ++k) pcr[k] = ((const float4*)WR)[(k << 6) + lane];
      }
      const float* fvb = fvw + (size_t)l * N * F + (blk << 4);
#pragma unroll
      for (int i = 0; i < 4; ++i) pf0[i] = ((const float4*)(fvb + (size_t)rv0 * F))[i];
#pragma unroll
      for (int i = 0; i < 4; ++i) pf1[i] = ((const float4*)(fvb + (size_t)rv1 * F))[i];
    }
    gbar_wait(bar, genc, blk, wid, lane);

    // ====== Stage C: LN2, mix, ffn_k -> relu^2 -> fvw col-panel; ffn_r ======
    {
      float2 sx2 = ld_c2(sxbuf + i0);
      ((float2*)s_tmp)[tid] = sx2;
      lbar();
      float4 x2q[4];
#pragma unroll
      for (int k = 0; k < 4; ++k) x2q[k] = ((const float4*)s_tmp)[(k << 6) + lane];
      ln16(x2q, ln2w + l * N, ln2b + l * N, lane);
      if (blk == 0 && wid == 0) {
#pragma unroll
        for (int k = 0; k < 4; ++k) ((float4*)sto)[(k << 6) + lane] = x2q[k];
      }
      float4 mk[4];
#pragma unroll
      for (int k = 0; k < 4; ++k) {
        float4 s0 = ((const float4*)st_l)[(k << 6) + lane];
        mk[k] = mix4(x2q[k], s0, ((const float4*)(fmk + l * N))[(k << 6) + lane]);
      }
      float d0 = 0.f, d1 = 0.f;
#pragma unroll
      for (int k = 0; k < 4; ++k) {
        d0 += dot4(pk0[k], mk[k]);
        d1 += dot4(pk1[k], mk[k]);
      }
      d0 = wred(d0);
      d1 = wred(d1);
      if (lane == 0) {
        float t0 = fmaxf(d0, 0.f);
        s_kk[wid] = t0 * t0;
        float t1 = fmaxf(d1, 0.f);
        s_kk[8 + wid] = t1 * t1;
      }
      if (wid >= 4) {
        float4 mr[4];
#pragma unroll
        for (int k = 0; k < 4; ++k) {
          float4 s0 = ((const float4*)st_l)[(k << 6) + lane];
          mr[k] = mix4(x2q[k], s0, ((const float4*)(fmr + l * N))[(k << 6) + lane]);
        }
        float dr = 0.f;
#pragma unroll
        for (int k = 0; k < 4; ++k) dr += dot4(pcr[k], mr[k]);
        dr = wred(dr);
        if (lane == 0) st_c(r2buf + rR, sigmoidf(dr));
      }
      lbar();
      float4 K0 = ((const float4*)s_kk)[0];
      float4 K1 = ((const float4*)s_kk)[1];
      float4 K2 = ((const float4*)s_kk)[2];
      float4 K3 = ((const float4*)s_kk)[3];
      float dv0 = dot4(pf0[0], K0) + dot4(pf0[1], K1) + dot4(pf0[2], K2) + dot4(pf0[3], K3);
      float dv1 = dot4(pf1[0], K0) + dot4(pf1[1], K1) + dot4(pf1[2], K2) + dot4(pf1[3], K3);
      unsafeAtomicAdd(facc + rv0, dv0);
      unsafeAtomicAdd(facc + rv1, dv1);
    }
    gbar_arrive(bar, ++genc, blk, tid);
    // ---- prefetch next layer's A weights during barrier wait ----
    if (l + 1 < NLAYERS) {
      const float* W0 = ((wid < 4) ? kw : vw) + (l + 1) * nn + (size_t)rA * N;
#pragma unroll
      for (int k = 0; k < 4; ++k) pa0[k] = ((const float4*)W0)[(k << 6) + lane];
      if (wid < 4) {
        const float* W1 = rw + (l + 1) * nn + (size_t)rA * N;
#pragma unroll
        for (int k = 0; k < 4; ++k) pa1[k] = ((const float4*)W1)[(k << 6) + lane];
      }
    }
    gbar_wait(bar, genc, blk, wid, lane);
  }

  // ================= head: logits = head @ LN(x_final) =================
  {
    float2 sx2 = ld_c2(sxbuf + i0);
    float2 r22 = ld_c2(r2buf + i0);
    float2 fa2 = ld_c2(facc + i0);
    float2 xf2;
    xf2.x = sx2.x + r22.x * fa2.x;
    xf2.y = sx2.y + r22.y * fa2.y;
    ((float2*)s_tmp)[tid] = xf2;
    lbar();
    float4 xf[4];
#pragma unroll
    for (int k = 0; k < 4; ++k) xf[k] = ((const float4*)s_tmp)[(k << 6) + lane];
    ln16(xf, lnoutw, lnoutb, lane);
    int gw = (blk << 3) + wid;
    for (int base = gw * 4; base < VOCAB; base += GRID * 8 * 4) {
      float4 h[4][4];
#pragma unroll
      for (int rr = 0; rr < 4; ++rr) {
        int row = base + rr;
        if (row < VOCAB) {
          const float4* hp = (const float4*)(head + (size_t)row * N);
#pragma unroll
          for (int k = 0; k < 4; ++k) h[rr][k] = hp[(k << 6) + lane];
        }
      }
#pragma unroll
      for (int rr = 0; rr < 4; ++rr) {
        int row = base + rr;
        if (row < VOCAB) {
          float d = 0.f;
#pragma unroll
          for (int k = 0; k < 4; ++k) d += dot4(h[rr][k], xf[k]);
          d = wred(d);
          if (lane == 0) logits[row] = d;
        }
      }
    }
  }
}

extern "C" void kernel_launch(void* const* d_in, const int* in_sizes, int n_in,
                              void* d_out, int out_size, void* d_ws, size_t ws_size,
                              hipStream_t stream) {
  const int* ctx = (const int*)d_in[0];
  const float* state = (const float*)d_in[1];
  const float* emb = (const float*)d_in[2];
  const float* ln0w = (const float*)d_in[3];
  const float* ln0b = (const float*)d_in[4];
  const float* ln1w = (const float*)d_in[5];
  const float* ln1b = (const float*)d_in[6];
  const float* amk = (const float*)d_in[7];
  const float* amv = (const float*)d_in[8];
  const float* amr = (const float*)d_in[9];
  const float* tf = (const float*)d_in[10];
  const float* td = (const float*)d_in[11];
  const float* kw = (const float*)d_in[12];
  const float* vw = (const float*)d_in[13];
  const float* rw = (const float*)d_in[14];
  const float* ow = (const float*)d_in[15];
  const float* ln2w = (const float*)d_in[16];
  const float* ln2b = (const float*)d_in[17];
  const float* fmk = (const float*)d_in[18];
  const float* fmr = (const float*)d_in[19];
  const float* fkw = (const float*)d_in[20];
  const float* fvw = (const float*)d_in[21];
  const float* frw = (const float*)d_in[22];
  const float* lnoutw = (const float*)d_in[23];
  const float* lnoutb = (const float*)d_in[24];
  const float* head = (const float*)d_in[25];
  float* out = (float*)d_out;
  float* ws = (float*)d_ws;
  unsigned* bar = (unsigned*)((char*)d_ws + BAR_OFF_BYTES);

  hipMemsetAsync(bar, 0, BAR_DWORDS * sizeof(unsigned), stream);

  void* args[] = {&ctx, &state, &emb, &ln0w, &ln0b, &ln1w, &ln1b,
                  &amk, &amv, &amr, &tf, &td, &kw, &vw, &rw, &ow,
                  &ln2w, &ln2b, &fmk, &fmr, &fkw, &fvw, &frw,
                  &lnoutw, &lnoutb, &head, &out, &ws, &bar};
  hipLaunchCooperativeKernel((const void*)k_rwkv, dim3(GRID), dim3(BLOCK),
                             args, 0, stream);
}

// Round 7
// 841.360 us; speedup vs baseline: 1.2554x; 1.0620x over previous
//
#include <hip/hip_runtime.h>
#include <math.h>

#define N 1024
#define F 4096
#define NLAYERS 24
#define VOCAB 50277
#define GRID 256
#define BLOCK 512   // 8 waves/block, 1 block per CU

// barrier region (in ws at byte offset 64 KB): arrive[256] flags, one 64B line each
#define BAR_OFF_BYTES 65536
#define LINE 16
#define BAR_DWORDS (256 * LINE)

__device__ __forceinline__ float dot4(float4 a, float4 b) {
  return fmaf(a.x, b.x, fmaf(a.y, b.y, fmaf(a.z, b.z, a.w * b.w)));
}
__device__ __forceinline__ float wred(float v) {
#pragma unroll
  for (int o = 32; o > 0; o >>= 1) v += __shfl_down(v, o, 64);
  return v;
}
__device__ __forceinline__ float bfly(float v) {
#pragma unroll
  for (int o = 1; o < 64; o <<= 1) v += __shfl_xor(v, o, 64);
  return v;
}
__device__ __forceinline__ float sigmoidf(float x) { return 1.f / (1.f + expf(-x)); }

// coherent (agent-scope) ops at the device coherent point (LLC)
__device__ __forceinline__ float2 ld_c2(const float* p) {
  unsigned long long u = __hip_atomic_load((const unsigned long long*)p,
                                           __ATOMIC_RELAXED, __HIP_MEMORY_SCOPE_AGENT);
  float2 f;
  f.x = __uint_as_float((unsigned)u);
  f.y = __uint_as_float((unsigned)(u >> 32));
  return f;
}
__device__ __forceinline__ void st_c(float* p, float v) {
  __hip_atomic_store(p, v, __ATOMIC_RELAXED, __HIP_MEMORY_SCOPE_AGENT);
}
__device__ __forceinline__ unsigned ld_cu(const unsigned* p) {
  return __hip_atomic_load(p, __ATOMIC_RELAXED, __HIP_MEMORY_SCOPE_AGENT);
}
__device__ __forceinline__ void st_cu(unsigned* p, unsigned v) {
  __hip_atomic_store(p, v, __ATOMIC_RELAXED, __HIP_MEMORY_SCOPE_AGENT);
}

// intra-block barrier: LDS visibility only
__device__ __forceinline__ void lbar() {
  asm volatile("s_waitcnt lgkmcnt(0)" ::: "memory");
  __builtin_amdgcn_s_barrier();
}

// arrive: drain everything once, block-sync, publish flag
__device__ __forceinline__ void gbar_arrive(unsigned* arr, unsigned gen, int blk,
                                            int tid) {
  asm volatile("s_waitcnt vmcnt(0) lgkmcnt(0)" ::: "memory");
  __builtin_amdgcn_s_barrier();
  if (tid == 0) st_cu(arr + blk * LINE, gen);
}
// wave 0 (vmcnt-clean: no prefetch issued before this): sweep all 256 flags,
// then signal the other waves through LDS.
__device__ __forceinline__ void sweep_signal(const unsigned* arr, unsigned gen,
                                             int lane, unsigned* s_gen) {
  for (;;) {
    bool ok = true;
#pragma unroll
    for (int i = 0; i < 4; ++i)
      ok &= (ld_cu(arr + (lane * 4 + i) * LINE) >= gen);
    if (__all(ok)) break;
    __builtin_amdgcn_s_sleep(1);
  }
  __hip_atomic_store(s_gen, gen, __ATOMIC_RELAXED, __HIP_MEMORY_SCOPE_WORKGROUP);
}
// waves 1-7: spin on LDS flag (lgkmcnt only — vector prefetch stays in flight)
__device__ __forceinline__ void lds_wait(const unsigned* s_gen, unsigned gen) {
  while (__hip_atomic_load(s_gen, __ATOMIC_RELAXED, __HIP_MEMORY_SCOPE_WORKGROUP) < gen)
    __builtin_amdgcn_s_sleep(1);
}

// redundant-per-wave LayerNorm of the 16 lane-columns held in q[4]
__device__ __forceinline__ void ln16(float4* q, const float* __restrict__ w,
                                     const float* __restrict__ b, int lane) {
  float s = 0.f, sq = 0.f;
#pragma unroll
  for (int k = 0; k < 4; ++k) {
    s += q[k].x + q[k].y + q[k].z + q[k].w;
    sq += dot4(q[k], q[k]);
  }
  s = bfly(s);
  sq = bfly(sq);
  float mu = s * (1.f / N);
  float rstd = rsqrtf(sq * (1.f / N) - mu * mu + 1e-5f);
#pragma unroll
  for (int k = 0; k < 4; ++k) {
    float4 w4 = ((const float4*)w)[(k << 6) + lane];
    float4 b4 = ((const float4*)b)[(k << 6) + lane];
    q[k].x = (q[k].x - mu) * rstd * w4.x + b4.x;
    q[k].y = (q[k].y - mu) * rstd * w4.y + b4.y;
    q[k].z = (q[k].z - mu) * rstd * w4.z + b4.z;
    q[k].w = (q[k].w - mu) * rstd * w4.w + b4.w;
  }
}

__device__ __forceinline__ float4 mix4(float4 a, float4 s, float4 m) {
  float4 r;
  r.x = a.x * m.x + s.x * (1.f - m.x);
  r.y = a.y * m.y + s.y * (1.f - m.y);
  r.z = a.z * m.z + s.z * (1.f - m.z);
  r.w = a.w * m.w + s.w * (1.f - m.w);
  return r;
}

__device__ __forceinline__ void wkv1(float k, float v, float r, float aa, float bb,
                                     float pp, float tf, float td, float& rab,
                                     float& naa, float& nbb, float& npp) {
  float ww = tf + k;
  float q = fmaxf(pp, ww);
  float e1 = expf(pp - q);
  float e2 = expf(ww - q);
  float a = e1 * aa + e2 * v;
  float b = e1 * bb + e2;
  rab = r * a / b;
  float ww2 = pp + td;
  float q2 = fmaxf(ww2, k);
  float f1 = expf(ww2 - q2);
  float f2 = expf(k - q2);
  naa = f1 * aa + f2 * v;
  nbb = f1 * bb + f2;
  npp = q2;
}

__global__ __launch_bounds__(BLOCK, 1) void k_rwkv(
    const int* __restrict__ ctx, const float* __restrict__ state,
    const float* __restrict__ emb, const float* __restrict__ ln0w,
    const float* __restrict__ ln0b, const float* __restrict__ ln1w,
    const float* __restrict__ ln1b, const float* __restrict__ amk,
    const float* __restrict__ amv, const float* __restrict__ amr,
    const float* __restrict__ tf, const float* __restrict__ td,
    const float* __restrict__ kw, const float* __restrict__ vw,
    const float* __restrict__ rw, const float* __restrict__ ow,
    const float* __restrict__ ln2w, const float* __restrict__ ln2b,
    const float* __restrict__ fmk, const float* __restrict__ fmr,
    const float* __restrict__ fkw, const float* __restrict__ fvw,
    const float* __restrict__ frw, const float* __restrict__ lnoutw,
    const float* __restrict__ lnoutb, const float* __restrict__ head,
    float* __restrict__ out, float* __restrict__ ws, unsigned* __restrict__ bar) {
  __shared__ __align__(16) float s_vx[N];   // layer input x (read in stage B)
  __shared__ __align__(16) float s_tmp[N];  // staging: rab / sx / xf
  __shared__ __align__(16) float s_kk[16];
  __shared__ unsigned s_gen;

  const int tid = threadIdx.x;
  const int lane = tid & 63;
  const int wid = tid >> 6;
  const int blk = blockIdx.x;
  const int i0 = 2 * tid;
  const size_t nn = (size_t)N * N;

  if (tid == 0) s_gen = 0;
  __syncthreads();

  float* logits = out;
  float* st_out = out + VOCAB;
  float* sxbuf = ws;
  float* kbuf = ws + N;
  float* vbuf = ws + 2 * N;
  float* rbuf = ws + 3 * N;
  float* r2buf = ws + 4 * N;
  float* facc8 = ws + 5 * N;   // 8 copies of N
  unsigned genc = 0;

  // prefetch registers
  float4 pa0[4], pa1[4], pb[4], pk0[4], pk1[4], pcr[4], pf0[4], pf1[4];

  const int rA = (blk << 2) + (wid & 3);   // kw/vw/rw row for this wave
  const int rB = (blk << 2) + wid;         // ow row (wid<4)
  const int rR = (blk << 2) + (wid - 4);   // frw row (wid>=4)
  const int gk0 = (blk << 4) + wid;        // fkw rows
  const int gk1 = gk0 + 8;
  const int rv0 = (tid + (blk << 2)) & (N - 1);          // fvw panel rows
  const int rv1 = (tid + (blk << 2) + 512) & (N - 1);

  // ---- initial prefetch: stage A, layer 0 (no barrier pending) ----
  {
    const float* W0 = ((wid < 4) ? kw : vw) + (size_t)rA * N;
#pragma unroll
    for (int k = 0; k < 4; ++k) pa0[k] = ((const float4*)W0)[(k << 6) + lane];
    if (wid < 4) {
      const float* W1 = rw + (size_t)rA * N;
#pragma unroll
      for (int k = 0; k < 4; ++k) pa1[k] = ((const float4*)W1)[(k << 6) + lane];
    }
  }

  for (int l = 0; l < NLAYERS; ++l) {
    const float* st_l = state + (size_t)l * 5 * N;
    float* sto = st_out + (size_t)l * 5 * N;

    // ================= Stage A: x, LN1, mix, k/v/r GEMVs =================
    {
      float2 xin;
      if (l == 0) {
        int t1 = ctx[1], t0c = ctx[0];
        float2 e1 = ((const float2*)(emb + (size_t)t1 * N))[tid];
        float2 e0 = ((const float2*)(emb + (size_t)t0c * N))[tid];
        xin.x = (e1.x * 4.f + e0.x) * 0.2f;
        xin.y = (e1.y * 4.f + e0.y) * 0.2f;
      } else {
        float2 sx2 = ld_c2(sxbuf + i0);
        float2 r22 = ld_c2(r2buf + i0);
        float fax = 0.f, fay = 0.f;
#pragma unroll
        for (int c = 0; c < 8; ++c) {
          float2 t = ld_c2(facc8 + c * N + i0);
          fax += t.x;
          fay += t.y;
        }
        xin.x = sx2.x + r22.x * fax;
        xin.y = sx2.y + r22.y * fay;
      }
      ((float2*)s_vx)[tid] = xin;
      lbar();
      float4 xq[4];
#pragma unroll
      for (int k = 0; k < 4; ++k) xq[k] = ((const float4*)s_vx)[(k << 6) + lane];
      if (l == 0) {
        ln16(xq, ln0w, ln0b, lane);   // xq = x (post-ln0)
        if (wid == 1) {
#pragma unroll
          for (int k = 0; k < 4; ++k) ((float4*)s_vx)[(k << 6) + lane] = xq[k];
        }
        // visible to stage B via gbar_arrive's lgkm drain + barrier
      }
      float4 xl[4];
#pragma unroll
      for (int k = 0; k < 4; ++k) xl[k] = xq[k];
      ln16(xl, ln1w + l * N, ln1b + l * N, lane);
      if (blk == 4 && wid == 1) {
#pragma unroll
        for (int k = 0; k < 4; ++k) ((float4*)(sto + N))[(k << 6) + lane] = xl[k];
      }
      if (wid < 4) {
        float4 mk[4], mr[4];
#pragma unroll
        for (int k = 0; k < 4; ++k) {
          float4 s1 = ((const float4*)(st_l + N))[(k << 6) + lane];
          mk[k] = mix4(xl[k], s1, ((const float4*)(amk + l * N))[(k << 6) + lane]);
          mr[k] = mix4(xl[k], s1, ((const float4*)(amr + l * N))[(k << 6) + lane]);
        }
        float d0 = 0.f, d1 = 0.f;
#pragma unroll
        for (int k = 0; k < 4; ++k) {
          d0 += dot4(pa0[k], mk[k]);
          d1 += dot4(pa1[k], mr[k]);
        }
        d0 = wred(d0);
        d1 = wred(d1);
        if (lane == 0) {
          st_c(kbuf + rA, d0);
          st_c(rbuf + rA, sigmoidf(d1));
        }
      } else {
        float4 mv[4];
#pragma unroll
        for (int k = 0; k < 4; ++k) {
          float4 s1 = ((const float4*)(st_l + N))[(k << 6) + lane];
          mv[k] = mix4(xl[k], s1, ((const float4*)(amv + l * N))[(k << 6) + lane]);
        }
        float d0 = 0.f;
#pragma unroll
        for (int k = 0; k < 4; ++k) d0 += dot4(pa0[k], mv[k]);
        d0 = wred(d0);
        if (lane == 0) st_c(vbuf + rA, d0);
      }
    }
    gbar_arrive(bar, ++genc, blk, tid);
    {
      auto pfB = [&]() {
        if (wid < 4) {
          const float* WB = ow + l * nn + (size_t)rB * N;
#pragma unroll
          for (int k = 0; k < 4; ++k) pb[k] = ((const float4*)WB)[(k << 6) + lane];
        }
      };
      if (wid == 0) {
        sweep_signal(bar, genc, lane, &s_gen);
        pfB();
      } else {
        pfB();
        lds_wait(&s_gen, genc);
      }
    }

    // ================= Stage B: WKV (per-thread) + ow GEMV =================
    {
      if (tid < 32)  // zero own rows of all 8 facc copies for stage C
        st_c(facc8 + (tid >> 2) * N + (blk << 2) + (tid & 3), 0.f);
      float2 k2 = ld_c2(kbuf + i0);
      float2 v2 = ld_c2(vbuf + i0);
      float2 r2v = ld_c2(rbuf + i0);
      float2 aa2 = ((const float2*)(st_l + 2 * N))[tid];
      float2 bb2 = ((const float2*)(st_l + 3 * N))[tid];
      float2 pp2 = ((const float2*)(st_l + 4 * N))[tid];
      float2 tf2 = ((const float2*)(tf + l * N))[tid];
      float2 td2 = ((const float2*)(td + l * N))[tid];
      float2 rab2, naa2, nbb2, npp2;
      wkv1(k2.x, v2.x, r2v.x, aa2.x, bb2.x, pp2.x, tf2.x, td2.x, rab2.x, naa2.x, nbb2.x, npp2.x);
      wkv1(k2.y, v2.y, r2v.y, aa2.y, bb2.y, pp2.y, tf2.y, td2.y, rab2.y, naa2.y, nbb2.y, npp2.y);
      ((float2*)s_tmp)[tid] = rab2;
      if (blk == 1) ((float2*)(sto + 2 * N))[tid] = naa2;
      if (blk == 2) ((float2*)(sto + 3 * N))[tid] = nbb2;
      if (blk == 3) ((float2*)(sto + 4 * N))[tid] = npp2;
      lbar();
      if (wid < 4) {
        float4 rq[4];
#pragma unroll
        for (int k = 0; k < 4; ++k) rq[k] = ((const float4*)s_tmp)[(k << 6) + lane];
        float d = 0.f;
#pragma unroll
        for (int k = 0; k < 4; ++k) d += dot4(pb[k], rq[k]);
        d = wred(d);
        if (lane == 0) st_c(sxbuf + rB, s_vx[rB] + d);
      }
    }
    gbar_arrive(bar, ++genc, blk, tid);
    {
      auto pfC = [&]() {
        const float* fkw_l = fkw + (size_t)l * F * N;
#pragma unroll
        for (int k = 0; k < 4; ++k)
          pk0[k] = ((const float4*)(fkw_l + (size_t)gk0 * N))[(k << 6) + lane];
#pragma unroll
        for (int k = 0; k < 4; ++k)
          pk1[k] = ((const float4*)(fkw_l + (size_t)gk1 * N))[(k << 6) + lane];
        if (wid >= 4) {
          const float* WR = frw + l * nn + (size_t)rR * N;
#pragma unroll
          for (int k = 0; k < 4; ++k) pcr[k] = ((const float4*)WR)[(k << 6) + lane];
        }
        const float* fvb = fvw + (size_t)l * N * F + (blk << 4);
#pragma unroll
        for (int i = 0; i < 4; ++i) pf0[i] = ((const float4*)(fvb + (size_t)rv0 * F))[i];
#pragma unroll
        for (int i = 0; i < 4; ++i) pf1[i] = ((const float4*)(fvb + (size_t)rv1 * F))[i];
      };
      if (wid == 0) {
        sweep_signal(bar, genc, lane, &s_gen);
        pfC();
      } else {
        pfC();
        lds_wait(&s_gen, genc);
      }
    }

    // ====== Stage C: LN2, mix, ffn_k -> relu^2 -> fvw col-panel; ffn_r ======
    {
      float2 sx2 = ld_c2(sxbuf + i0);
      ((float2*)s_tmp)[tid] = sx2;
      lbar();
      float4 x2q[4];
#pragma unroll
      for (int k = 0; k < 4; ++k) x2q[k] = ((const float4*)s_tmp)[(k << 6) + lane];
      ln16(x2q, ln2w + l * N, ln2b + l * N, lane);
      if (blk == 5 && wid == 1) {
#pragma unroll
        for (int k = 0; k < 4; ++k) ((float4*)sto)[(k << 6) + lane] = x2q[k];
      }
      float4 mk[4];
#pragma unroll
      for (int k = 0; k < 4; ++k) {
        float4 s0 = ((const float4*)st_l)[(k << 6) + lane];
        mk[k] = mix4(x2q[k], s0, ((const float4*)(fmk + l * N))[(k << 6) + lane]);
      }
      float d0 = 0.f, d1 = 0.f;
#pragma unroll
      for (int k = 0; k < 4; ++k) {
        d0 += dot4(pk0[k], mk[k]);
        d1 += dot4(pk1[k], mk[k]);
      }
      d0 = wred(d0);
      d1 = wred(d1);
      if (lane == 0) {
        float t0 = fmaxf(d0, 0.f);
        s_kk[wid] = t0 * t0;
        float t1 = fmaxf(d1, 0.f);
        s_kk[8 + wid] = t1 * t1;
      }
      if (wid >= 4) {
        float4 mr[4];
#pragma unroll
        for (int k = 0; k < 4; ++k) {
          float4 s0 = ((const float4*)st_l)[(k << 6) + lane];
          mr[k] = mix4(x2q[k], s0, ((const float4*)(fmr + l * N))[(k << 6) + lane]);
        }
        float dr = 0.f;
#pragma unroll
        for (int k = 0; k < 4; ++k) dr += dot4(pcr[k], mr[k]);
        dr = wred(dr);
        if (lane == 0) st_c(r2buf + rR, sigmoidf(dr));
      }
      lbar();
      float4 K0 = ((const float4*)s_kk)[0];
      float4 K1 = ((const float4*)s_kk)[1];
      float4 K2 = ((const float4*)s_kk)[2];
      float4 K3 = ((const float4*)s_kk)[3];
      float dv0 = dot4(pf0[0], K0) + dot4(pf0[1], K1) + dot4(pf0[2], K2) + dot4(pf0[3], K3);
      float dv1 = dot4(pf1[0], K0) + dot4(pf1[1], K1) + dot4(pf1[2], K2) + dot4(pf1[3], K3);
      float* fc = facc8 + (blk & 7) * N;
      unsafeAtomicAdd(fc + rv0, dv0);
      unsafeAtomicAdd(fc + rv1, dv1);
    }
    gbar_arrive(bar, ++genc, blk, tid);
    {
      auto pfA = [&]() {
        if (l + 1 < NLAYERS) {
          const float* W0 = ((wid < 4) ? kw : vw) + (l + 1) * nn + (size_t)rA * N;
#pragma unroll
          for (int k = 0; k < 4; ++k) pa0[k] = ((const float4*)W0)[(k << 6) + lane];
          if (wid < 4) {
            const float* W1 = rw + (l + 1) * nn + (size_t)rA * N;
#pragma unroll
            for (int k = 0; k < 4; ++k) pa1[k] = ((const float4*)W1)[(k << 6) + lane];
          }
        }
      };
      if (wid == 0) {
        sweep_signal(bar, genc, lane, &s_gen);
        pfA();
      } else {
        pfA();
        lds_wait(&s_gen, genc);
      }
    }
  }

  // ================= head: logits = head @ LN(x_final) =================
  {
    float2 sx2 = ld_c2(sxbuf + i0);
    float2 r22 = ld_c2(r2buf + i0);
    float fax = 0.f, fay = 0.f;
#pragma unroll
    for (int c = 0; c < 8; ++c) {
      float2 t = ld_c2(facc8 + c * N + i0);
      fax += t.x;
      fay += t.y;
    }
    float2 xf2;
    xf2.x = sx2.x + r22.x * fax;
    xf2.y = sx2.y + r22.y * fay;
    ((float2*)s_tmp)[tid] = xf2;
    lbar();
    float4 xf[4];
#pragma unroll
    for (int k = 0; k < 4; ++k) xf[k] = ((const float4*)s_tmp)[(k << 6) + lane];
    ln16(xf, lnoutw, lnoutb, lane);
    int gw = (blk << 3) + wid;
    for (int base = gw * 4; base < VOCAB; base += GRID * 8 * 4) {
      float4 h[4][4];
#pragma unroll
      for (int rr = 0; rr < 4; ++rr) {
        int row = base + rr;
        if (row < VOCAB) {
          const float4* hp = (const float4*)(head + (size_t)row * N);
#pragma unroll
          for (int k = 0; k < 4; ++k) h[rr][k] = hp[(k << 6) + lane];
        }
      }
#pragma unroll
      for (int rr = 0; rr < 4; ++rr) {
        int row = base + rr;
        if (row < VOCAB) {
          float d = 0.f;
#pragma unroll
          for (int k = 0; k < 4; ++k) d += dot4(h[rr][k], xf[k]);
          d = wred(d);
          if (lane == 0) logits[row] = d;
        }
      }
    }
  }
}

extern "C" void kernel_launch(void* const* d_in, const int* in_sizes, int n_in,
                              void* d_out, int out_size, void* d_ws, size_t ws_size,
                              hipStream_t stream) {
  const int* ctx = (const int*)d_in[0];
  const float* state = (const float*)d_in[1];
  const float* emb = (const float*)d_in[2];
  const float* ln0w = (const float*)d_in[3];
  const float* ln0b = (const float*)d_in[4];
  const float* ln1w = (const float*)d_in[5];
  const float* ln1b = (const float*)d_in[6];
  const float* amk = (const float*)d_in[7];
  const float* amv = (const float*)d_in[8];
  const float* amr = (const float*)d_in[9];
  const float* tf = (const float*)d_in[10];
  const float* td = (const float*)d_in[11];
  const float* kw = (const float*)d_in[12];
  const float* vw = (const float*)d_in[13];
  const float* rw = (const float*)d_in[14];
  const float* ow = (const float*)d_in[15];
  const float* ln2w = (const float*)d_in[16];
  const float* ln2b = (const float*)d_in[17];
  const float* fmk = (const float*)d_in[18];
  const float* fmr = (const float*)d_in[19];
  const float* fkw = (const float*)d_in[20];
  const float* fvw = (const float*)d_in[21];
  const float* frw = (const float*)d_in[22];
  const float* lnoutw = (const float*)d_in[23];
  const float* lnoutb = (const float*)d_in[24];
  const float* head = (const float*)d_in[25];
  float* out = (float*)d_out;
  float* ws = (float*)d_ws;
  unsigned* bar = (unsigned*)((char*)d_ws + BAR_OFF_BYTES);

  hipMemsetAsync(bar, 0, BAR_DWORDS * sizeof(unsigned), stream);

  void* args[] = {&ctx, &state, &emb, &ln0w, &ln0b, &ln1w, &ln1b,
                  &amk, &amv, &amr, &tf, &td, &kw, &vw, &rw, &ow,
                  &ln2w, &ln2b, &fmk, &fmr, &fkw, &fvw, &frw,
                  &lnoutw, &lnoutb, &head, &out, &ws, &bar};
  hipLaunchCooperativeKernel((const void*)k_rwkv, dim3(GRID), dim3(BLOCK),
                             args, 0, stream);
}

// Round 8
// 616.433 us; speedup vs baseline: 1.7135x; 1.3649x over previous
//
#include <hip/hip_runtime.h>
#include <math.h>

#define N 1024
#define F 4096
#define NLAYERS 24
#define VOCAB 50277
#define GRID 256
#define BLOCK 512   // 8 waves/block, 1 block per CU

// ws layout (floats): r2buf @0 (N); sxacc @N (2 parities x 8 copies x N);
// facc @N+16384 (same). barrier flags @ byte 135168: arrive[256], 64B lines.
#define SXACC_OFF N
#define FACC_OFF (N + 16384)
#define BAR_OFF_BYTES 135168
#define LINE 16
#define BAR_DWORDS (256 * LINE)
#define WS_CLEAR_BYTES (BAR_OFF_BYTES + BAR_DWORDS * 4)

__device__ __forceinline__ float dot4(float4 a, float4 b) {
  return fmaf(a.x, b.x, fmaf(a.y, b.y, fmaf(a.z, b.z, a.w * b.w)));
}
__device__ __forceinline__ float wred(float v) {
#pragma unroll
  for (int o = 32; o > 0; o >>= 1) v += __shfl_down(v, o, 64);
  return v;
}
__device__ __forceinline__ float bfly(float v) {
#pragma unroll
  for (int o = 1; o < 64; o <<= 1) v += __shfl_xor(v, o, 64);
  return v;
}
__device__ __forceinline__ float sigmoidf(float x) { return 1.f / (1.f + expf(-x)); }

// coherent (agent-scope) ops at the device coherent point (LLC)
__device__ __forceinline__ float2 ld_c2(const float* p) {
  unsigned long long u = __hip_atomic_load((const unsigned long long*)p,
                                           __ATOMIC_RELAXED, __HIP_MEMORY_SCOPE_AGENT);
  float2 f;
  f.x = __uint_as_float((unsigned)u);
  f.y = __uint_as_float((unsigned)(u >> 32));
  return f;
}
__device__ __forceinline__ void st_c(float* p, float v) {
  __hip_atomic_store(p, v, __ATOMIC_RELAXED, __HIP_MEMORY_SCOPE_AGENT);
}
__device__ __forceinline__ unsigned ld_cu(const unsigned* p) {
  return __hip_atomic_load(p, __ATOMIC_RELAXED, __HIP_MEMORY_SCOPE_AGENT);
}
__device__ __forceinline__ void st_cu(unsigned* p, unsigned v) {
  __hip_atomic_store(p, v, __ATOMIC_RELAXED, __HIP_MEMORY_SCOPE_AGENT);
}

// intra-block barrier: LDS visibility only
__device__ __forceinline__ void lbar() {
  asm volatile("s_waitcnt lgkmcnt(0)" ::: "memory");
  __builtin_amdgcn_s_barrier();
}

__device__ __forceinline__ void gbar_arrive(unsigned* arr, unsigned gen, int blk,
                                            int tid) {
  asm volatile("s_waitcnt vmcnt(0) lgkmcnt(0)" ::: "memory");
  __builtin_amdgcn_s_barrier();
  if (tid == 0) st_cu(arr + blk * LINE, gen);
}
// wave 0 (vmcnt-clean): sweep all 256 flags, signal others through LDS
__device__ __forceinline__ void sweep_signal(const unsigned* arr, unsigned gen,
                                             int lane, unsigned* s_gen) {
  for (;;) {
    bool ok = true;
#pragma unroll
    for (int i = 0; i < 4; ++i)
      ok &= (ld_cu(arr + (lane * 4 + i) * LINE) >= gen);
    if (__all(ok)) break;
    __builtin_amdgcn_s_sleep(1);
  }
  __hip_atomic_store(s_gen, gen, __ATOMIC_RELAXED, __HIP_MEMORY_SCOPE_WORKGROUP);
}
// waves 1-7: spin on LDS flag (vector prefetch stays in flight)
__device__ __forceinline__ void lds_wait(const unsigned* s_gen, unsigned gen) {
  while (__hip_atomic_load(s_gen, __ATOMIC_RELAXED, __HIP_MEMORY_SCOPE_WORKGROUP) < gen)
    __builtin_amdgcn_s_sleep(1);
}

// redundant-per-wave LayerNorm of 16 lane-columns in q[4] (full N vector/wave)
__device__ __forceinline__ void ln16(float4* q, const float* __restrict__ w,
                                     const float* __restrict__ b, int lane) {
  float s = 0.f, sq = 0.f;
#pragma unroll
  for (int k = 0; k < 4; ++k) {
    s += q[k].x + q[k].y + q[k].z + q[k].w;
    sq += dot4(q[k], q[k]);
  }
  s = bfly(s);
  sq = bfly(sq);
  float mu = s * (1.f / N);
  float rstd = rsqrtf(sq * (1.f / N) - mu * mu + 1e-5f);
#pragma unroll
  for (int k = 0; k < 4; ++k) {
    float4 w4 = ((const float4*)w)[(k << 6) + lane];
    float4 b4 = ((const float4*)b)[(k << 6) + lane];
    q[k].x = (q[k].x - mu) * rstd * w4.x + b4.x;
    q[k].y = (q[k].y - mu) * rstd * w4.y + b4.y;
    q[k].z = (q[k].z - mu) * rstd * w4.z + b4.z;
    q[k].w = (q[k].w - mu) * rstd * w4.w + b4.w;
  }
}

__device__ __forceinline__ float4 mix4(float4 a, float4 s, float4 m) {
  float4 r;
  r.x = a.x * m.x + s.x * (1.f - m.x);
  r.y = a.y * m.y + s.y * (1.f - m.y);
  r.z = a.z * m.z + s.z * (1.f - m.z);
  r.w = a.w * m.w + s.w * (1.f - m.w);
  return r;
}

__device__ __forceinline__ void wkv1(float k, float v, float r, float aa, float bb,
                                     float pp, float tf, float td, float& rab,
                                     float& naa, float& nbb, float& npp) {
  float ww = tf + k;
  float q = fmaxf(pp, ww);
  float e1 = expf(pp - q);
  float e2 = expf(ww - q);
  float a = e1 * aa + e2 * v;
  float b = e1 * bb + e2;
  rab = r * a / b;
  float ww2 = pp + td;
  float q2 = fmaxf(ww2, k);
  float f1 = expf(ww2 - q2);
  float f2 = expf(k - q2);
  naa = f1 * aa + f2 * v;
  nbb = f1 * bb + f2;
  npp = q2;
}

__global__ __launch_bounds__(BLOCK, 1) void k_rwkv(
    const int* __restrict__ ctx, const float* __restrict__ state,
    const float* __restrict__ emb, const float* __restrict__ ln0w,
    const float* __restrict__ ln0b, const float* __restrict__ ln1w,
    const float* __restrict__ ln1b, const float* __restrict__ amk,
    const float* __restrict__ amv, const float* __restrict__ amr,
    const float* __restrict__ tf, const float* __restrict__ td,
    const float* __restrict__ kw, const float* __restrict__ vw,
    const float* __restrict__ rw, const float* __restrict__ ow,
    const float* __restrict__ ln2w, const float* __restrict__ ln2b,
    const float* __restrict__ fmk, const float* __restrict__ fmr,
    const float* __restrict__ fkw, const float* __restrict__ fvw,
    const float* __restrict__ frw, const float* __restrict__ lnoutw,
    const float* __restrict__ lnoutb, const float* __restrict__ head,
    float* __restrict__ out, float* __restrict__ ws, unsigned* __restrict__ bar) {
  __shared__ __align__(16) float s_vx[N];   // layer input x
  __shared__ __align__(16) float s_sx[N];   // sx (attn output), reused next layer
  __shared__ __align__(16) float s_kk[16];
  __shared__ __align__(16) float s_ex[16];  // k[4],v[4],r[4],rab[4] exchange
  __shared__ unsigned s_gen;

  const int tid = threadIdx.x;
  const int lane = tid & 63;
  const int wid = tid >> 6;
  const int blk = blockIdx.x;
  const int i0 = 2 * tid;
  const size_t nn = (size_t)N * N;

  if (tid == 0) s_gen = 0;
  __syncthreads();

  float* logits = out;
  float* st_out = out + VOCAB;
  float* r2buf = ws;
  float* sxacc = ws + SXACC_OFF;  // [2][8][N]
  float* facc = ws + FACC_OFF;    // [2][8][N]
  unsigned genc = 0;

  // XCD-team row/col ownership: 4 blocks with same (blk%8) share a 16-col panel
  const int xcd = blk & 7, sgrp = blk >> 3;
  const int jm = sgrp & 3, gg = sgrp >> 2;
  const int tt = xcd + (gg << 3);          // team [0,64)
  const int c0 = (tt << 4) + (jm << 2);    // own 4 rows/cols base

  const int rowA = c0 + (wid & 3);         // kw/vw/rw row for this wave
  const int gk0 = (blk << 4) + wid, gk1 = gk0 + 8;  // fkw rows
  const int rR = (blk << 2) + (wid & 3);   // frw/r2 row (wid>=4)
  const int rv0 = (tid + (blk << 2)) & (N - 1);   // panel-GEMV rows
  const int rv1 = (rv0 + 512) & (N - 1);

  float4 pa0[4], pa1[4], pow0, pow1, pk0[4], pk1[4], pcr[4], pf0[4], pf1[4];

  // ---- initial prefetch: layer 0 stage AB ----
  {
    const float* W0 = ((wid < 4) ? kw : vw) + (size_t)rowA * N;
#pragma unroll
    for (int k = 0; k < 4; ++k) pa0[k] = ((const float4*)W0)[(k << 6) + lane];
    if (wid < 4) {
      const float* W1 = rw + (size_t)rowA * N;
#pragma unroll
      for (int k = 0; k < 4; ++k) pa1[k] = ((const float4*)W1)[(k << 6) + lane];
    }
    pow0 = *(const float4*)(ow + (size_t)rv0 * N + c0);
    pow1 = *(const float4*)(ow + (size_t)rv1 * N + c0);
  }

  for (int l = 0; l < NLAYERS; ++l) {
    const float* st_l = state + (size_t)l * 5 * N;
    float* sto = st_out + (size_t)l * 5 * N;
    const int p = l & 1;

    // ========= Stage AB: x, LN1, mix, k/v/r, WKV(own 4), ow col-panel =========
    {
      // early independent loads for WKV
      float kaa = 0.f, kbb = 0.f, kpp = 0.f, ktf = 0.f, ktd = 0.f;
      if (tid < 4) {
        int ii = c0 + tid;
        kaa = st_l[2 * N + ii];
        kbb = st_l[3 * N + ii];
        kpp = st_l[4 * N + ii];
        ktf = tf[l * N + ii];
        ktd = td[l * N + ii];
      }
      // zero sxacc[1-p] (accumulated by AB(l+1), 2 barriers away)
      if (tid < 32) st_c(sxacc + (1 - p) * 8192 + blk * 32 + tid, 0.f);

      float2 xin;
      if (l == 0) {
        int t1 = ctx[1], t0c = ctx[0];
        float2 e1 = ((const float2*)(emb + (size_t)t1 * N))[tid];
        float2 e0 = ((const float2*)(emb + (size_t)t0c * N))[tid];
        xin.x = (e1.x * 4.f + e0.x) * 0.2f;
        xin.y = (e1.y * 4.f + e0.y) * 0.2f;
      } else {
        float2 r22 = ld_c2(r2buf + i0);
        const float* fb = facc + (1 - p) * 8192;
        float fax = 0.f, fay = 0.f;
#pragma unroll
        for (int c = 0; c < 8; ++c) {
          float2 t2 = ld_c2(fb + c * N + i0);
          fax += t2.x;
          fay += t2.y;
        }
        xin.x = s_sx[i0] + r22.x * fax;
        xin.y = s_sx[i0 + 1] + r22.y * fay;
      }
      ((float2*)s_vx)[tid] = xin;
      lbar();
      float4 xq[4];
#pragma unroll
      for (int k = 0; k < 4; ++k) xq[k] = ((const float4*)s_vx)[(k << 6) + lane];
      if (l == 0) {
        ln16(xq, ln0w, ln0b, lane);
        lbar();  // everyone done reading raw x
        if (wid == 1) {
#pragma unroll
          for (int k = 0; k < 4; ++k) ((float4*)s_vx)[(k << 6) + lane] = xq[k];
        }
        // visible to stage C via gbar_arrive's lgkm drain
      }
      float4 xl[4];
#pragma unroll
      for (int k = 0; k < 4; ++k) xl[k] = xq[k];
      ln16(xl, ln1w + l * N, ln1b + l * N, lane);
      if (blk == 4 && wid == 1) {
#pragma unroll
        for (int k = 0; k < 4; ++k) ((float4*)(sto + N))[(k << 6) + lane] = xl[k];
      }
      if (wid < 4) {
        float dK = 0.f, dR = 0.f;
#pragma unroll
        for (int k = 0; k < 4; ++k) {
          float4 s1 = ((const float4*)(st_l + N))[(k << 6) + lane];
          float4 mk = mix4(xl[k], s1, ((const float4*)(amk + l * N))[(k << 6) + lane]);
          float4 mr = mix4(xl[k], s1, ((const float4*)(amr + l * N))[(k << 6) + lane]);
          dK += dot4(pa0[k], mk);
          dR += dot4(pa1[k], mr);
        }
        dK = wred(dK);
        dR = wred(dR);
        if (lane == 0) {
          s_ex[wid] = dK;
          s_ex[8 + wid] = sigmoidf(dR);
        }
      } else {
        float dV = 0.f;
#pragma unroll
        for (int k = 0; k < 4; ++k) {
          float4 s1 = ((const float4*)(st_l + N))[(k << 6) + lane];
          float4 mv = mix4(xl[k], s1, ((const float4*)(amv + l * N))[(k << 6) + lane]);
          dV += dot4(pa0[k], mv);
        }
        dV = wred(dV);
        if (lane == 0) s_ex[4 + (wid & 3)] = dV;
      }
      lbar();
      if (tid < 4) {
        float kv = s_ex[tid], vv = s_ex[4 + tid], rr = s_ex[8 + tid];
        float rab, naa, nbb, npp;
        wkv1(kv, vv, rr, kaa, kbb, kpp, ktf, ktd, rab, naa, nbb, npp);
        int ii = c0 + tid;
        sto[2 * N + ii] = naa;
        sto[3 * N + ii] = nbb;
        sto[4 * N + ii] = npp;
        s_ex[12 + tid] = rab;
      }
      lbar();
      float4 rab4 = *((const float4*)(s_ex + 12));  // LDS broadcast
      float* sxa = sxacc + p * 8192 + xcd * N;
      unsafeAtomicAdd(sxa + rv0, dot4(pow0, rab4));
      unsafeAtomicAdd(sxa + rv1, dot4(pow1, rab4));
    }
    gbar_arrive(bar, ++genc, blk, tid);
    {
      auto pfC = [&]() {
        const float* fkw_l = fkw + (size_t)l * F * N;
#pragma unroll
        for (int k = 0; k < 4; ++k)
          pk0[k] = ((const float4*)(fkw_l + (size_t)gk0 * N))[(k << 6) + lane];
#pragma unroll
        for (int k = 0; k < 4; ++k)
          pk1[k] = ((const float4*)(fkw_l + (size_t)gk1 * N))[(k << 6) + lane];
        if (wid >= 4) {
          const float* WR = frw + l * nn + (size_t)rR * N;
#pragma unroll
          for (int k = 0; k < 4; ++k) pcr[k] = ((const float4*)WR)[(k << 6) + lane];
        }
        const float* fvb = fvw + (size_t)l * N * F + (blk << 4);
#pragma unroll
        for (int i = 0; i < 4; ++i) pf0[i] = ((const float4*)(fvb + (size_t)rv0 * F))[i];
#pragma unroll
        for (int i = 0; i < 4; ++i) pf1[i] = ((const float4*)(fvb + (size_t)rv1 * F))[i];
      };
      if (wid == 0) {
        sweep_signal(bar, genc, lane, &s_gen);
        pfC();
      } else {
        pfC();
        lds_wait(&s_gen, genc);
      }
    }

    // ========= Stage C: sx, LN2, mix, ffn_k, ffn_r, fvw col-panel =========
    {
      // zero facc[1-p] (accumulated by C(l+1), 2+ barriers away)
      if (tid < 32) st_c(facc + (1 - p) * 8192 + blk * 32 + tid, 0.f);
      const float* sb = sxacc + p * 8192;
      float fax = 0.f, fay = 0.f;
#pragma unroll
      for (int c = 0; c < 8; ++c) {
        float2 t2 = ld_c2(sb + c * N + i0);
        fax += t2.x;
        fay += t2.y;
      }
      float2 sx2;
      sx2.x = s_vx[i0] + fax;
      sx2.y = s_vx[i0 + 1] + fay;
      ((float2*)s_sx)[tid] = sx2;   // persists into next layer's AB
      lbar();
      float4 x2q[4];
#pragma unroll
      for (int k = 0; k < 4; ++k) x2q[k] = ((const float4*)s_sx)[(k << 6) + lane];
      ln16(x2q, ln2w + l * N, ln2b + l * N, lane);
      if (blk == 5 && wid == 1) {
#pragma unroll
        for (int k = 0; k < 4; ++k) ((float4*)sto)[(k << 6) + lane] = x2q[k];
      }
      float4 mk[4];
#pragma unroll
      for (int k = 0; k < 4; ++k) {
        float4 s0 = ((const float4*)st_l)[(k << 6) + lane];
        mk[k] = mix4(x2q[k], s0, ((const float4*)(fmk + l * N))[(k << 6) + lane]);
      }
      float d0 = 0.f, d1 = 0.f;
#pragma unroll
      for (int k = 0; k < 4; ++k) {
        d0 += dot4(pk0[k], mk[k]);
        d1 += dot4(pk1[k], mk[k]);
      }
      d0 = wred(d0);
      d1 = wred(d1);
      if (lane == 0) {
        float t0 = fmaxf(d0, 0.f);
        s_kk[wid] = t0 * t0;
        float t1 = fmaxf(d1, 0.f);
        s_kk[8 + wid] = t1 * t1;
      }
      if (wid >= 4) {
        float dr = 0.f;
#pragma unroll
        for (int k = 0; k < 4; ++k) {
          float4 s0 = ((const float4*)st_l)[(k << 6) + lane];
          float4 mr = mix4(x2q[k], s0, ((const float4*)(fmr + l * N))[(k << 6) + lane]);
          dr += dot4(pcr[k], mr);
        }
        dr = wred(dr);
        if (lane == 0) st_c(r2buf + rR, sigmoidf(dr));
      }
      lbar();
      float4 K0 = ((const float4*)s_kk)[0];
      float4 K1 = ((const float4*)s_kk)[1];
      float4 K2 = ((const float4*)s_kk)[2];
      float4 K3 = ((const float4*)s_kk)[3];
      float* fc = facc + p * 8192 + xcd * N;
      unsafeAtomicAdd(fc + rv0, dot4(pf0[0], K0) + dot4(pf0[1], K1) +
                                    dot4(pf0[2], K2) + dot4(pf0[3], K3));
      unsafeAtomicAdd(fc + rv1, dot4(pf1[0], K0) + dot4(pf1[1], K1) +
                                    dot4(pf1[2], K2) + dot4(pf1[3], K3));
    }
    gbar_arrive(bar, ++genc, blk, tid);
    {
      auto pfA = [&]() {
        if (l + 1 < NLAYERS) {
          const float* W0 = ((wid < 4) ? kw : vw) + (l + 1) * nn + (size_t)rowA * N;
#pragma unroll
          for (int k = 0; k < 4; ++k) pa0[k] = ((const float4*)W0)[(k << 6) + lane];
          if (wid < 4) {
            const float* W1 = rw + (l + 1) * nn + (size_t)rowA * N;
#pragma unroll
            for (int k = 0; k < 4; ++k) pa1[k] = ((const float4*)W1)[(k << 6) + lane];
          }
          const float* owl = ow + (l + 1) * nn;
          pow0 = *(const float4*)(owl + (size_t)rv0 * N + c0);
          pow1 = *(const float4*)(owl + (size_t)rv1 * N + c0);
        }
      };
      if (wid == 0) {
        sweep_signal(bar, genc, lane, &s_gen);
        pfA();
      } else {
        pfA();
        lds_wait(&s_gen, genc);
      }
    }
  }

  // ================= head: logits = head @ LN(x_final) =================
  {
    float2 r22 = ld_c2(r2buf + i0);
    const float* fb = facc + ((NLAYERS - 1) & 1) * 8192;
    float fax = 0.f, fay = 0.f;
#pragma unroll
    for (int c = 0; c < 8; ++c) {
      float2 t2 = ld_c2(fb + c * N + i0);
      fax += t2.x;
      fay += t2.y;
    }
    float2 xf2;
    xf2.x = s_sx[i0] + r22.x * fax;
    xf2.y = s_sx[i0 + 1] + r22.y * fay;
    ((float2*)s_vx)[tid] = xf2;
    lbar();
    float4 xf[4];
#pragma unroll
    for (int k = 0; k < 4; ++k) xf[k] = ((const float4*)s_vx)[(k << 6) + lane];
    ln16(xf, lnoutw, lnoutb, lane);
    int gw = (blk << 3) + wid;
    for (int base = gw * 4; base < VOCAB; base += GRID * 8 * 4) {
      float4 h[4][4];
#pragma unroll
      for (int rr = 0; rr < 4; ++rr) {
        int row = base + rr;
        if (row < VOCAB) {
          const float4* hp = (const float4*)(head + (size_t)row * N);
#pragma unroll
          for (int k = 0; k < 4; ++k) h[rr][k] = hp[(k << 6) + lane];
        }
      }
#pragma unroll
      for (int rr = 0; rr < 4; ++rr) {
        int row = base + rr;
        if (row < VOCAB) {
          float d = 0.f;
#pragma unroll
          for (int k = 0; k < 4; ++k) d += dot4(h[rr][k], xf[k]);
          d = wred(d);
          if (lane == 0) logits[row] = d;
        }
      }
    }
  }
}

extern "C" void kernel_launch(void* const* d_in, const int* in_sizes, int n_in,
                              void* d_out, int out_size, void* d_ws, size_t ws_size,
                              hipStream_t stream) {
  const int* ctx = (const int*)d_in[0];
  const float* state = (const float*)d_in[1];
  const float* emb = (const float*)d_in[2];
  const float* ln0w = (const float*)d_in[3];
  const float* ln0b = (const float*)d_in[4];
  const float* ln1w = (const float*)d_in[5];
  const float* ln1b = (const float*)d_in[6];
  const float* amk = (const float*)d_in[7];
  const float* amv = (const float*)d_in[8];
  const float* amr = (const float*)d_in[9];
  const float* tf = (const float*)d_in[10];
  const float* td = (const float*)d_in[11];
  const float* kw = (const float*)d_in[12];
  const float* vw = (const float*)d_in[13];
  const float* rw = (const float*)d_in[14];
  const float* ow = (const float*)d_in[15];
  const float* ln2w = (const float*)d_in[16];
  const float* ln2b = (const float*)d_in[17];
  const float* fmk = (const float*)d_in[18];
  const float* fmr = (const float*)d_in[19];
  const float* fkw = (const float*)d_in[20];
  const float* fvw = (const float*)d_in[21];
  const float* frw = (const float*)d_in[22];
  const float* lnoutw = (const float*)d_in[23];
  const float* lnoutb = (const float*)d_in[24];
  const float* head = (const float*)d_in[25];
  float* out = (float*)d_out;
  float* ws = (float*)d_ws;
  unsigned* bar = (unsigned*)((char*)d_ws + BAR_OFF_BYTES);

  hipMemsetAsync(d_ws, 0, WS_CLEAR_BYTES, stream);

  void* args[] = {&ctx, &state, &emb, &ln0w, &ln0b, &ln1w, &ln1b,
                  &amk, &amv, &amr, &tf, &td, &kw, &vw, &rw, &ow,
                  &ln2w, &ln2b, &fmk, &fmr, &fkw, &fvw, &frw,
                  &lnoutw, &lnoutb, &head, &out, &ws, &bar};
  hipLaunchCooperativeKernel((const void*)k_rwkv, dim3(GRID), dim3(BLOCK),
                             args, 0, stream);
}